// Round 1
// baseline (423.137 us; speedup 1.0000x reference)
//
#include <hip/hip_runtime.h>
#include <cstddef>

// StreamingISTFT: denormalize -> irfft(2048) over freq axis -> window -> overlap-add.
// B=8, F=1024(+Nyquist pad), T=2048, HOP=512, FRAME_LEN=2048.
// irfft(2048) done as complex IFFT(1024) (real-packing trick), IFFT(1024) done as
// four-step 32x32 so every global access is contiguous in t. FFT32 fully in registers.

#define TDIM 2048
#define FDIM 1024

static constexpr int kBREV[32] = {0,16,8,24,4,20,12,28,2,18,10,26,6,22,14,30,
                                  1,17,9,25,5,21,13,29,3,19,11,27,7,23,15,31};
// e^{+2*pi*i*r/32}, r=0..15 (inverse-transform sign)
static constexpr float kTR[16] = {
  1.0f, 0.98078528040323044f, 0.92387953251128674f, 0.83146961230254524f,
  0.70710678118654757f, 0.55557023301960218f, 0.38268343236508978f, 0.19509032201612825f,
  0.0f, -0.19509032201612825f, -0.38268343236508978f, -0.55557023301960218f,
  -0.70710678118654757f, -0.83146961230254524f, -0.92387953251128674f, -0.98078528040323044f};
static constexpr float kTI[16] = {
  0.0f, 0.19509032201612825f, 0.38268343236508978f, 0.55557023301960218f,
  0.70710678118654757f, 0.83146961230254524f, 0.92387953251128674f, 0.98078528040323044f,
  1.0f, 0.98078528040323044f, 0.92387953251128674f, 0.83146961230254524f,
  0.70710678118654757f, 0.55557023301960218f, 0.38268343236508978f, 0.19509032201612825f};

// In-register radix-2 DIT FFT32 (inverse sign). Input must already be in
// bit-reversed order; output natural: out[m] = sum_k in_nat[k] e^{+2 pi i k m/32}.
__device__ __forceinline__ void ifft32_core(float ar[32], float ai[32]) {
  #pragma unroll
  for (int s = 0; s < 5; ++s) {
    const int half = 1 << s;
    const int tstep = 16 >> s;
    #pragma unroll
    for (int g = 0; g < 32; g += (half << 1)) {
      #pragma unroll
      for (int j = 0; j < half; ++j) {
        const float twr = kTR[j * tstep];
        const float twi = kTI[j * tstep];
        const int i0 = g + j, i1 = i0 + half;
        const float tr = twr * ar[i1] - twi * ai[i1];
        const float ti = twr * ai[i1] + twi * ar[i1];
        ar[i1] = ar[i0] - tr; ai[i1] = ai[i0] - ti;
        ar[i0] += tr;         ai[i0] += ti;
      }
    }
  }
}

__device__ __forceinline__ void ifft32_natural(float wr[32], float wi[32]) {
  float ar[32], ai[32];
  #pragma unroll
  for (int i = 0; i < 32; ++i) { ar[i] = wr[kBREV[i]]; ai[i] = wi[kBREV[i]]; }
  ifft32_core(ar, ai);
  #pragma unroll
  for (int i = 0; i < 32; ++i) { wr[i] = ar[i]; wi[i] = ai[i]; }
}

// Given S1 = X[k], S2 = X[1024-k], T = e^{2 pi i k/2048}:
//   W[k]      = (S1 + conj(S2)) + i*T*(S1 - conj(S2))       -> (w1r, w1i)
//   W[1024-k] = (S2 + conj(S1)) + i*(-conj(T))*(S2-conj(S1))-> (w2r, w2i)
__device__ __forceinline__ void wpair(float s1r, float s1i, float s2r, float s2i,
                                      float tr, float ti,
                                      float& w1r, float& w1i, float& w2r, float& w2i) {
  const float Pre = s1r + s2r, Pim = s1i - s2i;
  const float Qre = s1r - s2r, Qim = s1i + s2i;
  const float u = tr * Qim + ti * Qre;
  const float v = tr * Qre - ti * Qim;
  w1r = Pre - u; w1i = Pim + v;
  w2r = Pre + u; w2i = v - Pim;
}

// Apply e^{2 pi i k1 m2 /1024} twiddle and store A[k1*32+m2][t].
__device__ __forceinline__ void store_class(float2* __restrict__ Ab, int k1, int t,
                                            const float wr[32], const float wi[32]) {
  #pragma unroll
  for (int m2 = 0; m2 < 32; ++m2) {
    float sn, cs;
    __sincosf(6.1359231515425649e-3f * (float)(k1 * m2), &sn, &cs);  // pi/512 * k1*m2
    const float vr = cs * wr[m2] - sn * wi[m2];
    const float vi = cs * wi[m2] + sn * wr[m2];
    Ab[(size_t)(k1 * 32 + m2) * TDIM + t] = make_float2(vr, vi);
  }
}

// Pass 1: denormalize + W packing + FFT32 over k2 (+ inter-stage twiddle).
// blockIdx: x = t-tile (8x256), y = class-group g (17), z = batch.
// g=0 -> class 0 (self-mirrored, DC/Nyquist specials); g=1 -> class 16 (self-mirrored);
// g>=2 -> dual classes {g-1, 33-g}.
__global__ __launch_bounds__(256) void istft_pass1(const float* __restrict__ in,
                                                   float2* __restrict__ A) {
  const int t = blockIdx.x * 256 + threadIdx.x;
  const int g = blockIdx.y;
  const int b = blockIdx.z;
  const float* re_p = in + ((size_t)b * 2 + 0) * ((size_t)FDIM * TDIM);
  const float* im_p = in + ((size_t)b * 2 + 1) * ((size_t)FDIM * TDIM);
  float2* Ab = A + (size_t)b * FDIM * TDIM;

  // fold: beta^(-1/alpha) / 2048  (irfft 1/N folded in)
  const float KS = (float)(exp((-1.0 / 0.65) * log(0.06)) / 2048.0);
  const float PE = 7.0f / 26.0f;  // ((1/alpha)-1)/2

  int k1a, k1b = 0; bool dual;
  if (g == 0)      { k1a = 0;  dual = false; }
  else if (g == 1) { k1a = 16; dual = false; }
  else             { k1a = g - 1; k1b = 32 - k1a; dual = true; }

  float sar[32], sai[32];
  #pragma unroll
  for (int k2 = 0; k2 < 32; ++k2) {
    const int k = k1a + 32 * k2;
    const float x = re_p[(size_t)k * TDIM + t];
    const float y = im_p[(size_t)k * TDIM + t];
    const float gm = KS * __powf(x * x + y * y, PE);
    sar[k2] = x * gm; sai[k2] = y * gm;
  }

  if (!dual) {
    if (g == 0) {
      // k=0 (DC): irfft ignores Im(X[0]); mirror is the zero Nyquist pad.
      // W[0] = S0r*(1+i)
      const float r0 = sar[0];
      sar[0] = r0; sai[0] = r0;
      // k=512 self-mirror: W = 2*conj(S)
      sar[16] =  2.0f * sar[16];
      sai[16] = -2.0f * sai[16];
      #pragma unroll
      for (int k2 = 1; k2 < 16; ++k2) {
        float sn, cs;
        __sincosf(3.0679615757712824e-3f * (float)(32 * k2), &sn, &cs);  // pi*k/1024
        float w1r, w1i, w2r, w2i;
        wpair(sar[k2], sai[k2], sar[32 - k2], sai[32 - k2], cs, sn, w1r, w1i, w2r, w2i);
        sar[k2] = w1r; sai[k2] = w1i; sar[32 - k2] = w2r; sai[32 - k2] = w2i;
      }
    } else {  // class 16: element k2 mirrors element 31-k2 within the class
      #pragma unroll
      for (int k2 = 0; k2 < 16; ++k2) {
        float sn, cs;
        __sincosf(3.0679615757712824e-3f * (float)(16 + 32 * k2), &sn, &cs);
        float w1r, w1i, w2r, w2i;
        wpair(sar[k2], sai[k2], sar[31 - k2], sai[31 - k2], cs, sn, w1r, w1i, w2r, w2i);
        sar[k2] = w1r; sai[k2] = w1i; sar[31 - k2] = w2r; sai[31 - k2] = w2i;
      }
    }
    ifft32_natural(sar, sai);
    store_class(Ab, k1a, t, sar, sai);
  } else {
    float sbr[32], sbi[32];
    #pragma unroll
    for (int k2 = 0; k2 < 32; ++k2) {
      const int k = k1b + 32 * k2;
      const float x = re_p[(size_t)k * TDIM + t];
      const float y = im_p[(size_t)k * TDIM + t];
      const float gm = KS * __powf(x * x + y * y, PE);
      sbr[k2] = x * gm; sbi[k2] = y * gm;
    }
    // mirror(a[k2]) = b[31-k2]; mirror(b[k2]) = a[31-k2]
    #pragma unroll
    for (int k2 = 0; k2 < 16; ++k2) {
      float sn1, cs1, sn2, cs2;
      __sincosf(3.0679615757712824e-3f * (float)(k1a + 32 * k2), &sn1, &cs1);
      __sincosf(3.0679615757712824e-3f * (float)(k1b + 32 * k2), &sn2, &cs2);
      float w1r, w1i, w2r, w2i, x1r, x1i, x2r, x2i;
      wpair(sar[k2], sai[k2], sbr[31 - k2], sbi[31 - k2], cs1, sn1, w1r, w1i, w2r, w2i);
      wpair(sbr[k2], sbi[k2], sar[31 - k2], sai[31 - k2], cs2, sn2, x1r, x1i, x2r, x2i);
      sar[k2] = w1r; sai[k2] = w1i; sbr[31 - k2] = w2r; sbi[31 - k2] = w2i;
      sbr[k2] = x1r; sbi[k2] = x1i; sar[31 - k2] = x2r; sai[31 - k2] = x2i;
    }
    ifft32_natural(sar, sai);
    store_class(Ab, k1a, t, sar, sai);
    ifft32_natural(sbr, sbi);
    store_class(Ab, k1b, t, sbr, sbi);
  }
}

// Pass 2: FFT32 over k1 (rows k1*32+m2) -> z[m2+32*m1]; x[2m]=Re z, x[2m+1]=Im z;
// multiply by inv_window; store frames[l][t].
__global__ __launch_bounds__(256) void istft_pass2(const float2* __restrict__ A,
                                                   const float* __restrict__ invw,
                                                   float* __restrict__ frames) {
  const int t  = blockIdx.x * 256 + threadIdx.x;
  const int m2 = blockIdx.y;
  const int b  = blockIdx.z;
  const float2* Ab = A + (size_t)b * FDIM * TDIM;
  float* fb = frames + (size_t)b * TDIM * TDIM;
  float ar[32], ai[32];
  #pragma unroll
  for (int i = 0; i < 32; ++i) {  // load directly in bit-reversed order
    const float2 v = Ab[(size_t)(kBREV[i] * 32 + m2) * TDIM + t];
    ar[i] = v.x; ai[i] = v.y;
  }
  ifft32_core(ar, ai);
  #pragma unroll
  for (int m1 = 0; m1 < 32; ++m1) {
    const int m = m2 + 32 * m1;
    fb[(size_t)(2 * m)     * TDIM + t] = ar[m1] * invw[2 * m];
    fb[(size_t)(2 * m + 1) * TDIM + t] = ai[m1] * invw[2 * m + 1];
  }
}

// Pass 3: overlap-add gather + transpose. out[b][512h+j] = sum_c frames[b][j+512c][h-c].
__global__ __launch_bounds__(256) void istft_pass3(const float* __restrict__ frames,
                                                   float* __restrict__ out) {
  __shared__ float tile[64][65];  // [j'][h'], +1 pad: transposed read is conflict-free
  const int j0 = blockIdx.x * 64;
  const int h0 = blockIdx.y * 64;
  const int b  = blockIdx.z;
  const int lane = threadIdx.x & 63;
  const int grp  = threadIdx.x >> 6;
  const float* fb = frames + (size_t)b * TDIM * TDIM;
  #pragma unroll
  for (int rr = grp; rr < 64; rr += 4) {
    const int j = j0 + rr;
    float acc = 0.0f;
    #pragma unroll
    for (int c = 0; c < 4; ++c) {
      const int hcol = h0 + lane - c;
      if (hcol >= 0) acc += fb[(size_t)(j + 512 * c) * TDIM + hcol];
    }
    tile[rr][lane] = acc;
  }
  __syncthreads();
  float* ob = out + (size_t)b * (size_t)(512 * 2048);
  #pragma unroll
  for (int hh = grp; hh < 64; hh += 4) {
    ob[(size_t)(h0 + hh) * 512 + j0 + lane] = tile[lane][hh];
  }
}

extern "C" void kernel_launch(void* const* d_in, const int* in_sizes, int n_in,
                              void* d_out, int out_size, void* d_ws, size_t ws_size,
                              hipStream_t stream) {
  (void)in_sizes; (void)n_in; (void)out_size;
  const float* in   = (const float*)d_in[0];
  const float* invw = (const float*)d_in[1];
  float* out = (float*)d_out;
  const size_t perA = (size_t)FDIM * TDIM * sizeof(float2);  // 16 MiB / batch
  const size_t perF = (size_t)TDIM * TDIM * sizeof(float);   // 16 MiB / batch
  int nb = (int)(ws_size / (perA + perF));
  if (nb < 1) nb = 1;
  if (nb > 8) nb = 8;
  for (int b0 = 0; b0 < 8; b0 += nb) {
    const int cnt = (8 - b0 < nb) ? (8 - b0) : nb;
    float2* A     = (float2*)d_ws;
    float* frames = (float*)((char*)d_ws + (size_t)cnt * perA);
    istft_pass1<<<dim3(8, 17, cnt), 256, 0, stream>>>(
        in + (size_t)b0 * 2 * FDIM * TDIM, A);
    istft_pass2<<<dim3(8, 32, cnt), 256, 0, stream>>>(A, invw, frames);
    istft_pass3<<<dim3(8, 32, cnt), 256, 0, stream>>>(
        frames, out + (size_t)b0 * (size_t)(512 * 2048));
  }
}